// Round 3
// baseline (970.938 us; speedup 1.0000x reference)
//
#include <hip/hip_runtime.h>

typedef short s8v __attribute__((ext_vector_type(8)));
typedef short s4v __attribute__((ext_vector_type(4)));
typedef float f4v __attribute__((ext_vector_type(4)));

#define HW     200704      // 448*448
#define NCH    192
#define PT     64          // pixels per tile
#define CMP    68          // channel-major LDS pitch (elements)
#define PMP    200         // pixel-major LDS pitch (elements)
#define GRID   512
#define NTILES 3136        // HW/PT

__device__ __forceinline__ float b2f(unsigned short u){
    unsigned int i = ((unsigned int)u) << 16; float f;
    __builtin_memcpy(&f, &i, 4); return f;
}
__device__ __forceinline__ unsigned short f2b(float f){
    unsigned int i; __builtin_memcpy(&i, &f, 4);
    i += 0x7FFFu + ((i >> 16) & 1u);
    return (unsigned short)(i >> 16);
}
// octet swizzle for pixel-major buffers: injective bank mapping
__device__ __forceinline__ int swz(int oct, int p){
    return (oct & ~7) | ((oct + 2*(p & 7)) & 7);
}

// ============================ prep ============================
__global__ void gsa_prep(const float* __restrict__ pre_w, const float* __restrict__ qkv_w,
                         const float* __restrict__ proj_w, unsigned short* __restrict__ wbf,
                         float* __restrict__ accs, unsigned int* __restrict__ ctr)
{
    int i = blockIdx.x*256 + threadIdx.x;
    if (i == 0) { ctr[0] = GRID; ctr[1] = GRID; }   // tickets 0..GRID-1 are implicit (blockIdx)
    if (i < 6528)   accs[i] = 0.f;
    if (i < 36864)  wbf[i]           = f2b(pre_w[i]);
    if (i < 110592) wbf[36864 + i]   = f2b(qkv_w[i]);
    if (i < 36864)  wbf[147456 + i]  = f2b(proj_w[i]);
}

// v global format: tile-contiguous pm rows, packed into the even-channel byte
// footprint of out-tile t:  u16 addr = 4*chunk*HW + 128*t + inner8,
// chunk = (linear_u16/128), i.e. exactly the bytes K3 block t overwrites.

// ============================ K1 ============================
__global__ __launch_bounds__(384, 3) void gsa_k1(
    const float* __restrict__ x,
    const float* __restrict__ lng,
    const float* __restrict__ lnb,
    const unsigned short* __restrict__ pre_wb,
    const float* __restrict__ pre_b,
    const unsigned short* __restrict__ qkv_wb,
    unsigned short* __restrict__ v_out,      // u16 view of d_out
    float* __restrict__ gram_red,
    float* __restrict__ sq_red,
    unsigned int* __restrict__ ctr)
{
    __shared__ __align__(16) unsigned char smem[26112*2 + 25600 + 512 + 1536];
    __shared__ int t_next_sh;
    unsigned short* bufA  = (unsigned short*)smem;              // cm [192][68]: x -> q
    unsigned short* bufP1 = (unsigned short*)(smem + 26112);    // pm xn -> cm k
    unsigned short* bufP2 = (unsigned short*)(smem + 2*26112);  // pm y -> pm v
    float* stats  = (float*)(smem + 2*26112 + 25600);           // [128]
    float* sq_lds = (float*)(smem + 2*26112 + 25600 + 512);     // [384]

    const int tid  = threadIdx.x;
    const int wid  = tid >> 6;     // 0..5
    const int lane = tid & 63;
    const int l15  = lane & 15;
    const int quad = lane >> 4;
    const int c0   = tid >> 3;     // 0..47
    const int oc8  = tid & 7;

    f4v gacc[4];
    #pragma unroll
    for (int g = 0; g < 4; ++g) gacc[g] = (f4v){0.f, 0.f, 0.f, 0.f};
    sq_lds[tid] = 0.f;

    int t = blockIdx.x;
    f4v xr[8];
    #pragma unroll
    for (int pass = 0; pass < 4; ++pass) {
        const float* gp = x + (size_t)(pass*48 + c0)*HW + t*PT + oc8*8;
        xr[2*pass]   = *(const f4v*)(gp);
        xr[2*pass+1] = *(const f4v*)(gp + 4);
    }

    while (t < NTILES) {
        // ---- phase A: ticket prefetch + stats zero + xr -> bufA cm ----
        if (tid == 0) t_next_sh = (int)atomicAdd(ctr, 1u);
        if (tid < 128) stats[tid] = 0.f;
        #pragma unroll
        for (int pass = 0; pass < 4; ++pass) {
            int c = pass*48 + c0;
            s8v w;
            #pragma unroll
            for (int r = 0; r < 4; ++r) { w[r] = (short)f2b(xr[2*pass][r]); w[4+r] = (short)f2b(xr[2*pass+1][r]); }
            *(s8v*)(bufA + c*CMP + oc8*8) = w;
        }
        __syncthreads();   // S1

        // ---- phase B: per-pixel mean/var partials via LDS float atomics ----
        {
            float s1 = 0.f, s2 = 0.f;
            #pragma unroll
            for (int i = 0; i < 32; ++i) {
                float v = b2f(bufA[(wid*32 + i)*CMP + lane]);
                s1 += v; s2 += v*v;
            }
            atomicAdd(&stats[lane], s1);
            atomicAdd(&stats[64 + lane], s2);
        }
        __syncthreads();   // S2

        // ---- phase C: normalize + transpose -> pm xn (bufP1) ----
        {
            const float mu = stats[lane] * (1.f/192.f);
            const float is = rsqrtf(fmaxf(stats[64 + lane]*(1.f/192.f) - mu*mu, 0.f) + 1e-5f);
            #pragma unroll
            for (int oo = 0; oo < 4; ++oo) {
                s8v w;
                #pragma unroll
                for (int j = 0; j < 8; ++j) {
                    int c = wid*32 + oo*8 + j;
                    float v = (b2f(bufA[c*CMP + lane]) - mu) * is;
                    v = v * lng[c] + lnb[c];
                    w[j] = (short)f2b(v);
                }
                *(s8v*)(bufP1 + lane*PMP + swz(wid*4 + oo, lane)*8) = w;
            }
        }
        __syncthreads();   // S3

        // ---- GEMM1: y = pre_w * xn + pre_b -> bufP2 pm ----
        {
            f4v acc[2][4];
            #pragma unroll
            for (int j = 0; j < 2; ++j)
                #pragma unroll
                for (int nt = 0; nt < 4; ++nt) acc[j][nt] = (f4v){0.f,0.f,0.f,0.f};
            #pragma unroll
            for (int ks = 0; ks < 6; ++ks) {
                s8v b[4];
                #pragma unroll
                for (int nt = 0; nt < 4; ++nt) {
                    int p = nt*16 + l15;
                    b[nt] = *(const s8v*)(bufP1 + p*PMP + swz(ks*4 + quad, p)*8);
                }
                #pragma unroll
                for (int j = 0; j < 2; ++j) {
                    s8v a = *(const s8v*)(pre_wb + (size_t)((wid*2 + j)*16 + l15)*NCH + ks*32 + quad*8);
                    #pragma unroll
                    for (int nt = 0; nt < 4; ++nt)
                        acc[j][nt] = __builtin_amdgcn_mfma_f32_16x16x32_bf16(a, b[nt], acc[j][nt], 0, 0, 0);
                }
            }
            #pragma unroll
            for (int j = 0; j < 2; ++j) {
                int cc = (wid*2 + j)*16 + quad*4;
                f4v pb4 = *(const f4v*)(pre_b + cc);
                int oct = cc >> 3, half = (cc >> 2) & 1;
                #pragma unroll
                for (int nt = 0; nt < 4; ++nt) {
                    int p = nt*16 + l15;
                    s4v w;
                    #pragma unroll
                    for (int r = 0; r < 4; ++r)
                        w[r] = (short)f2b(acc[j][nt][r] + pb4[r]);
                    *(s4v*)(bufP2 + p*PMP + swz(oct, p)*8 + half*4) = w;
                }
            }
        }
        __syncthreads();   // S4

        // ---- merged GEMM2: q,k,v in one pass over y ----
        f4v av[2][4];
        {
            f4v aq[2][4], ak[2][4];
            #pragma unroll
            for (int j = 0; j < 2; ++j)
                #pragma unroll
                for (int nt = 0; nt < 4; ++nt) {
                    aq[j][nt] = (f4v){0.f,0.f,0.f,0.f};
                    ak[j][nt] = (f4v){0.f,0.f,0.f,0.f};
                    av[j][nt] = (f4v){0.f,0.f,0.f,0.f};
                }
            #pragma unroll
            for (int ks = 0; ks < 6; ++ks) {
                s8v b[4];
                #pragma unroll
                for (int nt = 0; nt < 4; ++nt) {
                    int p = nt*16 + l15;
                    b[nt] = *(const s8v*)(bufP2 + p*PMP + swz(ks*4 + quad, p)*8);
                }
                #pragma unroll
                for (int j = 0; j < 2; ++j) {
                    const unsigned short* wr = qkv_wb + (size_t)(wid*32 + j*16 + l15)*NCH + ks*32 + quad*8;
                    s8v a0 = *(const s8v*)(wr);
                    s8v a1 = *(const s8v*)(wr + (size_t)192*NCH);
                    s8v a2 = *(const s8v*)(wr + (size_t)384*NCH);
                    #pragma unroll
                    for (int nt = 0; nt < 4; ++nt) {
                        aq[j][nt] = __builtin_amdgcn_mfma_f32_16x16x32_bf16(a0, b[nt], aq[j][nt], 0, 0, 0);
                        ak[j][nt] = __builtin_amdgcn_mfma_f32_16x16x32_bf16(a1, b[nt], ak[j][nt], 0, 0, 0);
                        av[j][nt] = __builtin_amdgcn_mfma_f32_16x16x32_bf16(a2, b[nt], av[j][nt], 0, 0, 0);
                    }
                }
            }
            // store q -> bufA cm, k -> bufP1 cm
            #pragma unroll
            for (int j = 0; j < 2; ++j)
                #pragma unroll
                for (int nt = 0; nt < 4; ++nt) {
                    int p = nt*16 + l15;
                    #pragma unroll
                    for (int r = 0; r < 4; ++r) {
                        int c = wid*32 + j*16 + quad*4 + r;
                        bufA[c*CMP + p]  = f2b(aq[j][nt][r]);
                        bufP1[c*CMP + p] = f2b(ak[j][nt][r]);
                    }
                }
        }
        __syncthreads();   // S5

        // ---- post-S5: next-tile prefetch, v->pm, sumsq, gram ----
        int tn = t_next_sh;
        if (tn < NTILES) {
            #pragma unroll
            for (int pass = 0; pass < 4; ++pass) {
                const float* gp = x + (size_t)(pass*48 + c0)*HW + tn*PT + oc8*8;
                xr[2*pass]   = *(const f4v*)(gp);
                xr[2*pass+1] = *(const f4v*)(gp + 4);
            }
        }
        // v accs -> bufP2 pm (overwrites y, consumed pre-S5)
        #pragma unroll
        for (int j = 0; j < 2; ++j) {
            int cc = wid*32 + j*16 + quad*4;
            int oct = cc >> 3, half = (cc >> 2) & 1;
            #pragma unroll
            for (int nt = 0; nt < 4; ++nt) {
                int p = nt*16 + l15;
                s4v w;
                #pragma unroll
                for (int r = 0; r < 4; ++r)
                    w[r] = (short)f2b(av[j][nt][r]);
                *(s4v*)(bufP2 + p*PMP + swz(oct, p)*8 + half*4) = w;
            }
        }
        // sumsq of q,k rows
        {
            const unsigned short* src = (tid < 192) ? (bufA + tid*CMP) : (bufP1 + (tid - 192)*CMP);
            float s = 0.f;
            #pragma unroll
            for (int o = 0; o < 8; ++o) {
                s4v lo = *(const s4v*)(src + o*8);
                s4v hi = *(const s4v*)(src + o*8 + 4);
                #pragma unroll
                for (int e = 0; e < 4; ++e) {
                    float a = b2f((unsigned short)lo[e]);
                    float b = b2f((unsigned short)hi[e]);
                    s += a*a + b*b;
                }
            }
            sq_lds[tid] += s;
        }
        // gram accumulate (h = wid)
        #pragma unroll
        for (int g = 0; g < 4; ++g) {
            int dm = g >> 1, em = g & 1;
            const unsigned short* qrow = bufA  + (wid*32 + dm*16 + l15)*CMP;
            const unsigned short* krow = bufP1 + (wid*32 + em*16 + l15)*CMP;
            #pragma unroll
            for (int ks = 0; ks < 2; ++ks) {
                int off = ks*32 + quad*8;
                s4v alo = *(const s4v*)(qrow + off), ahi = *(const s4v*)(qrow + off + 4);
                s4v blo = *(const s4v*)(krow + off), bhi = *(const s4v*)(krow + off + 4);
                s8v a = __builtin_shufflevector(alo, ahi, 0,1,2,3,4,5,6,7);
                s8v b = __builtin_shufflevector(blo, bhi, 0,1,2,3,4,5,6,7);
                gacc[g] = __builtin_amdgcn_mfma_f32_16x16x32_bf16(a, b, gacc[g], 0, 0, 0);
            }
        }
        __syncthreads();   // S6

        // ---- v global store (tile-contiguous packed format) ----
        #pragma unroll
        for (int q = 0; q < 4; ++q) {
            int idx = q*384 + tid;
            int p   = idx / 24;
            int col = (idx - p*24) * 8;
            s8v w = *(const s8v*)(bufP2 + p*PMP + col);
            *(s8v*)(v_out + (size_t)4*(idx >> 4)*HW + (size_t)128*t + (tid & 15)*8) = w;
        }
        t = tn;
    }

    #pragma unroll
    for (int g = 0; g < 4; ++g) {
        int dm = g >> 1, em = g & 1;
        #pragma unroll
        for (int r = 0; r < 4; ++r) {
            int d = dm*16 + quad*4 + r, e = em*16 + l15;
            atomicAdd(&gram_red[wid*1024 + d*32 + e], gacc[g][r]);
        }
    }
    atomicAdd(&sq_red[tid], sq_lds[tid]);
}

// ============================ K2 ============================
__global__ void gsa_k2(const float* __restrict__ gram_red, const float* __restrict__ sq_red,
                       const float* __restrict__ mn_w, const float* __restrict__ gating,
                       unsigned short* __restrict__ gm_out)
{
    __shared__ float attn[6144];
    __shared__ float mw[2048];
    __shared__ float inv[384];
    const int tid = threadIdx.x;
    for (int i = tid; i < 384; i += 256)
        inv[i] = 1.f / fmaxf(sqrtf(fmaxf(sq_red[i], 0.f)), 1e-12f);
    for (int i = tid; i < 2048; i += 256) mw[i] = mn_w[i];
    __syncthreads();
    for (int i = tid; i < 6144; i += 256) {
        int h = i >> 10, d = (i >> 5) & 31, e = i & 31;
        attn[i] = gram_red[i] * inv[h*32 + d] * inv[192 + h*32 + e];
    }
    __syncthreads();
    if (tid < 192) {
        int h = tid >> 5, d = tid & 31;
        float g1 = gating[h], g2 = gating[6 + h];
        const float* ar = attn + h*1024 + d*32;
        for (int e = 0; e < 32; ++e) {
            float m = 0.f, n = 0.f;
            for (int c2 = 0; c2 < 32; ++c2) {
                m += ar[c2] * mw[e*32 + c2];
                n += ar[c2] * mw[(e + 32)*32 + c2];
            }
            gm_out[h*1024 + d*32 + e] = f2b(g1*m + g2*n);
        }
    }
}

// ============================ K3 ============================
__global__ __launch_bounds__(384, 3) void gsa_k3(
    const float* __restrict__ cond,
    const float* __restrict__ x,
    const unsigned short* __restrict__ gm,
    const unsigned short* __restrict__ proj_wb,
    const unsigned short* v_in,     // u16 view of d_out
    float* out,                     // fp32 view of d_out
    unsigned int* __restrict__ ctr)
{
    __shared__ __align__(16) unsigned char smem[26112 + 25600 + 25600];
    __shared__ int t_next_sh;
    unsigned short* bufA = (unsigned short*)smem;                     // cm cond -> pm v -> cm bounce
    unsigned short* bufB = (unsigned short*)(smem + 26112);           // pm illu
    unsigned short* bufC = (unsigned short*)(smem + 26112 + 25600);   // pm sm

    const int tid  = threadIdx.x;
    const int wid  = tid >> 6;     // 0..5 == head
    const int lane = tid & 63;
    const int l15  = lane & 15;
    const int quad = lane >> 4;
    const int c0   = tid >> 3;
    const int oc8  = tid & 7;

    int t = blockIdx.x;
    f4v cr[8];
    s8v vr[4];
    #pragma unroll
    for (int pass = 0; pass < 4; ++pass) {
        const float* gp = cond + (size_t)(pass*48 + c0)*HW + t*PT + oc8*8;
        cr[2*pass]   = *(const f4v*)(gp);
        cr[2*pass+1] = *(const f4v*)(gp + 4);
    }
    #pragma unroll
    for (int q = 0; q < 4; ++q) {
        int idx = q*384 + tid;
        vr[q] = *(const s8v*)(v_in + (size_t)4*(idx >> 4)*HW + (size_t)128*t + (tid & 15)*8);
    }

    while (t < NTILES) {
        __syncthreads();   // S0: prev epilogue's bufA reads done
        if (tid == 0) t_next_sh = (int)atomicAdd(ctr + 1, 1u);
        // phase A: cr -> bufA cm
        #pragma unroll
        for (int pass = 0; pass < 4; ++pass) {
            int c = pass*48 + c0;
            s8v w;
            #pragma unroll
            for (int r = 0; r < 4; ++r) { w[r] = (short)f2b(cr[2*pass][r]); w[4+r] = (short)f2b(cr[2*pass+1][r]); }
            *(s8v*)(bufA + c*CMP + oc8*8) = w;
        }
        __syncthreads();   // S1
        // transpose -> bufB pm
        #pragma unroll
        for (int oo = 0; oo < 4; ++oo) {
            int oct = wid*4 + oo;
            s8v w;
            #pragma unroll
            for (int j = 0; j < 8; ++j)
                w[j] = (short)bufA[(oct*8 + j)*CMP + lane];
            *(s8v*)(bufB + lane*PMP + swz(oct, lane)*8) = w;
        }
        __syncthreads();   // S2
        // v stage: vr -> bufA pm (verbatim swizzled rows)
        #pragma unroll
        for (int q = 0; q < 4; ++q) {
            int idx = q*384 + tid;
            int p   = idx / 24;
            int col = (idx - p*24) * 8;
            *(s8v*)(bufA + p*PMP + col) = vr[q];
        }
        // prefetch next tile's cond + v
        int tn = t_next_sh;
        if (tn < NTILES) {
            #pragma unroll
            for (int pass = 0; pass < 4; ++pass) {
                const float* gp = cond + (size_t)(pass*48 + c0)*HW + tn*PT + oc8*8;
                cr[2*pass]   = *(const f4v*)(gp);
                cr[2*pass+1] = *(const f4v*)(gp + 4);
            }
            #pragma unroll
            for (int q = 0; q < 4; ++q) {
                int idx = q*384 + tid;
                vr[q] = *(const s8v*)(v_in + (size_t)4*(idx >> 4)*HW + (size_t)128*tn + (tid & 15)*8);
            }
        }
        __syncthreads();   // S3
        // mi MFMA + *v + softmax over head-dim -> bufC (h = wid)
        {
            const int h = wid;
            s8v a0 = *(const s8v*)(gm + h*1024 + l15*32 + quad*8);
            s8v a1 = *(const s8v*)(gm + h*1024 + (16 + l15)*32 + quad*8);
            #pragma unroll
            for (int nt = 0; nt < 4; ++nt) {
                int p = nt*16 + l15;
                s8v b = *(const s8v*)(bufB + p*PMP + swz(h*4 + quad, p)*8);
                f4v z = (f4v){0.f,0.f,0.f,0.f};
                f4v m0 = __builtin_amdgcn_mfma_f32_16x16x32_bf16(a0, b, z, 0, 0, 0);
                f4v m1 = __builtin_amdgcn_mfma_f32_16x16x32_bf16(a1, b, z, 0, 0, 0);
                int oct0 = h*4 + (quad >> 1), hf = (quad & 1)*4;
                s4v v0 = *(const s4v*)(bufA + p*PMP + swz(oct0, p)*8 + hf);
                s4v v1 = *(const s4v*)(bufA + p*PMP + swz(oct0 + 2, p)*8 + hf);
                float tv[8];
                #pragma unroll
                for (int r = 0; r < 4; ++r) {
                    tv[r]     = m0[r] * b2f((unsigned short)v0[r]);
                    tv[4 + r] = m1[r] * b2f((unsigned short)v1[r]);
                }
                float mx = tv[0];
                #pragma unroll
                for (int r = 1; r < 8; ++r) mx = fmaxf(mx, tv[r]);
                mx = fmaxf(mx, __shfl_xor(mx, 16));
                mx = fmaxf(mx, __shfl_xor(mx, 32));
                float s = 0.f;
                #pragma unroll
                for (int r = 0; r < 8; ++r) { tv[r] = __expf(tv[r] - mx); s += tv[r]; }
                s += __shfl_xor(s, 16);
                s += __shfl_xor(s, 32);
                float is = 1.f / s;
                s4v w0, w1;
                #pragma unroll
                for (int r = 0; r < 4; ++r) {
                    w0[r] = (short)f2b(tv[r] * is);
                    w1[r] = (short)f2b(tv[4 + r] * is);
                }
                int ca = h*32 + quad*4, cb = ca + 16;
                *(s4v*)(bufC + p*PMP + swz(ca >> 3, p)*8 + ((ca >> 2) & 1)*4) = w0;
                *(s4v*)(bufC + p*PMP + swz(cb >> 3, p)*8 + ((cb >> 2) & 1)*4) = w1;
            }
        }
        __syncthreads();   // S4
        // GEMM4 (proj) + x residual prefetch + bounce
        {
            f4v xr[8];
            #pragma unroll
            for (int pass = 0; pass < 4; ++pass) {
                const float* gp = x + (size_t)(pass*48 + c0)*HW + t*PT + oc8*8;
                xr[2*pass]   = *(const f4v*)(gp);
                xr[2*pass+1] = *(const f4v*)(gp + 4);
            }
            f4v acc[2][4];
            #pragma unroll
            for (int j = 0; j < 2; ++j)
                #pragma unroll
                for (int nt = 0; nt < 4; ++nt) acc[j][nt] = (f4v){0.f,0.f,0.f,0.f};
            #pragma unroll
            for (int ks = 0; ks < 6; ++ks) {
                s8v b[4];
                #pragma unroll
                for (int nt = 0; nt < 4; ++nt) {
                    int p = nt*16 + l15;
                    b[nt] = *(const s8v*)(bufC + p*PMP + swz(ks*4 + quad, p)*8);
                }
                #pragma unroll
                for (int j = 0; j < 2; ++j) {
                    s8v a = *(const s8v*)(proj_wb + (size_t)((wid*2 + j)*16 + l15)*NCH + ks*32 + quad*8);
                    #pragma unroll
                    for (int nt = 0; nt < 4; ++nt)
                        acc[j][nt] = __builtin_amdgcn_mfma_f32_16x16x32_bf16(a, b[nt], acc[j][nt], 0, 0, 0);
                }
            }
            // bounce: accs -> bufA cm (v reads finished pre-S4)
            #pragma unroll
            for (int j = 0; j < 2; ++j)
                #pragma unroll
                for (int nt = 0; nt < 4; ++nt) {
                    int p = nt*16 + l15;
                    #pragma unroll
                    for (int r = 0; r < 4; ++r) {
                        int c = wid*32 + j*16 + quad*4 + r;
                        bufA[c*CMP + p] = f2b(acc[j][nt][r]);
                    }
                }
            __syncthreads();   // S5
            // epilogue: out = proj + x
            #pragma unroll
            for (int pass = 0; pass < 4; ++pass) {
                int c = pass*48 + c0;
                f4v o0, o1;
                #pragma unroll
                for (int r = 0; r < 4; ++r) {
                    o0[r] = b2f(bufA[c*CMP + oc8*8 + r])     + xr[2*pass][r];
                    o1[r] = b2f(bufA[c*CMP + oc8*8 + 4 + r]) + xr[2*pass+1][r];
                }
                float* op = out + (size_t)c*HW + t*PT + oc8*8;
                *(f4v*)(op)     = o0;
                *(f4v*)(op + 4) = o1;
            }
        }
        t = tn;
    }
}

// ============================ launch ============================
extern "C" void kernel_launch(void* const* d_in, const int* in_sizes, int n_in,
                              void* d_out, int out_size, void* d_ws, size_t ws_size,
                              hipStream_t stream)
{
    (void)in_sizes; (void)n_in; (void)out_size; (void)ws_size;
    const float* x      = (const float*)d_in[0];
    const float* cond   = (const float*)d_in[1];
    const float* lng    = (const float*)d_in[2];
    const float* lnb    = (const float*)d_in[3];
    const float* pre_w  = (const float*)d_in[4];
    const float* pre_b  = (const float*)d_in[5];
    const float* qkv_w  = (const float*)d_in[6];
    const float* mn_w   = (const float*)d_in[7];
    const float* gating = (const float*)d_in[8];
    const float* proj_w = (const float*)d_in[9];

    // workspace layout:
    //   [0,24576)        gram_red (6144 f32)
    //   [24576,26112)    sq_red   (384 f32)
    //   [26112,38400)    gm       (6144 bf16)
    //   [38400,407040)   wbf: pre_w_bf16 | qkv_w_bf16 | proj_w_bf16
    //   [407040,407048)  tickets: ctr[0]=K1, ctr[1]=K3
    char* ws = (char*)d_ws;
    float* gram_red = (float*)ws;
    float* sq_red   = (float*)(ws + 24576);
    unsigned short* gm  = (unsigned short*)(ws + 26112);
    unsigned short* wbf = (unsigned short*)(ws + 38400);
    unsigned int* ctr   = (unsigned int*)(ws + 407040);
    unsigned short* pre_wb  = wbf;
    unsigned short* qkv_wb  = wbf + 36864;
    unsigned short* proj_wb = wbf + 147456;

    gsa_prep<<<432,  256, 0, stream>>>(pre_w, qkv_w, proj_w, wbf, gram_red, ctr);
    gsa_k1 <<<GRID,  384, 0, stream>>>(x, lng, lnb, pre_wb, pre_b, qkv_wb,
                                       (unsigned short*)d_out, gram_red, sq_red, ctr);
    gsa_k2 <<<1,     256, 0, stream>>>(gram_red, sq_red, mn_w, gating, gm);
    gsa_k3 <<<GRID,  384, 0, stream>>>(cond, x, gm, proj_wb,
                                       (const unsigned short*)d_out, (float*)d_out, ctr);
}

// Round 4
// 698.673 us; speedup vs baseline: 1.3897x; 1.3897x over previous
//
#include <hip/hip_runtime.h>

typedef short s8v __attribute__((ext_vector_type(8)));
typedef short s4v __attribute__((ext_vector_type(4)));
typedef float f4v __attribute__((ext_vector_type(4)));

#define HW     200704      // 448*448
#define NCH    192
#define PT     64          // pixels per tile
#define CMP    68          // channel-major LDS pitch (elements)
#define PMP    200         // pixel-major LDS pitch (elements)
#define GRID   512
#define NTILES 3136        // HW/PT

__device__ __forceinline__ float b2f(unsigned short u){
    unsigned int i = ((unsigned int)u) << 16; float f;
    __builtin_memcpy(&f, &i, 4); return f;
}
__device__ __forceinline__ unsigned short f2b(float f){
    unsigned int i; __builtin_memcpy(&i, &f, 4);
    i += 0x7FFFu + ((i >> 16) & 1u);
    return (unsigned short)(i >> 16);
}
// octet swizzle for pixel-major buffers: injective bank mapping
__device__ __forceinline__ int swz(int oct, int p){
    return (oct & ~7) | ((oct + 2*(p & 7)) & 7);
}

// ============================ prep ============================
__global__ void gsa_prep(const float* __restrict__ pre_w, const float* __restrict__ qkv_w,
                         const float* __restrict__ proj_w, unsigned short* __restrict__ wbf,
                         float* __restrict__ accs, unsigned int* __restrict__ ctr)
{
    int i = blockIdx.x*256 + threadIdx.x;
    if (i == 0) { ctr[0] = GRID; ctr[1] = GRID; }   // tickets 0..GRID-1 are implicit (blockIdx)
    if (i < 6528)   accs[i] = 0.f;
    if (i < 36864)  wbf[i]           = f2b(pre_w[i]);
    if (i < 110592) wbf[36864 + i]   = f2b(qkv_w[i]);
    if (i < 36864)  wbf[147456 + i]  = f2b(proj_w[i]);
}

// v global format: tile-contiguous pm rows, packed into the even-channel byte
// footprint of out-tile t:  u16 addr = 4*chunk*HW + 128*t + inner8,
// chunk = (linear_u16/128), i.e. exactly the bytes K3 block t overwrites.

// ============================ K1 ============================
// launch_bounds(384,2): cap 256 regs — structural pressure ~140 keeps 3 waves/SIMD.
// (384,3) in R3 capped at ~170 unified and spilled the 96-acc merged GEMM to scratch.
__global__ __launch_bounds__(384, 2) void gsa_k1(
    const float* __restrict__ x,
    const float* __restrict__ lng,
    const float* __restrict__ lnb,
    const unsigned short* __restrict__ pre_wb,
    const float* __restrict__ pre_b,
    const unsigned short* __restrict__ qkv_wb,
    unsigned short* __restrict__ v_out,      // u16 view of d_out
    float* __restrict__ gram_red,
    float* __restrict__ sq_red,
    unsigned int* __restrict__ ctr)
{
    __shared__ __align__(16) unsigned char smem[26112*2 + 25600 + 512 + 1536];
    __shared__ int t_next_sh;
    unsigned short* bufA  = (unsigned short*)smem;              // cm [192][68]: x -> q
    unsigned short* bufP1 = (unsigned short*)(smem + 26112);    // pm xn -> cm k
    unsigned short* bufP2 = (unsigned short*)(smem + 2*26112);  // pm y -> pm v
    float* stats  = (float*)(smem + 2*26112 + 25600);           // [128]
    float* sq_lds = (float*)(smem + 2*26112 + 25600 + 512);     // [384]

    const int tid  = threadIdx.x;
    const int wid  = tid >> 6;     // 0..5
    const int lane = tid & 63;
    const int l15  = lane & 15;
    const int quad = lane >> 4;
    const int c0   = tid >> 3;     // 0..47
    const int oc8  = tid & 7;

    f4v gacc[4];
    #pragma unroll
    for (int g = 0; g < 4; ++g) gacc[g] = (f4v){0.f, 0.f, 0.f, 0.f};
    sq_lds[tid] = 0.f;

    int t = blockIdx.x;
    f4v xr[8];
    #pragma unroll
    for (int pass = 0; pass < 4; ++pass) {
        const float* gp = x + (size_t)(pass*48 + c0)*HW + t*PT + oc8*8;
        xr[2*pass]   = *(const f4v*)(gp);
        xr[2*pass+1] = *(const f4v*)(gp + 4);
    }

    while (t < NTILES) {
        // ---- phase A: ticket prefetch + stats zero + xr -> bufA cm ----
        if (tid == 0) t_next_sh = (int)atomicAdd(ctr, 1u);
        if (tid < 128) stats[tid] = 0.f;
        #pragma unroll
        for (int pass = 0; pass < 4; ++pass) {
            int c = pass*48 + c0;
            s8v w;
            #pragma unroll
            for (int r = 0; r < 4; ++r) { w[r] = (short)f2b(xr[2*pass][r]); w[4+r] = (short)f2b(xr[2*pass+1][r]); }
            *(s8v*)(bufA + c*CMP + oc8*8) = w;
        }
        __syncthreads();   // S1

        // ---- phase B: per-pixel mean/var partials via LDS float atomics ----
        {
            float s1 = 0.f, s2 = 0.f;
            #pragma unroll
            for (int i = 0; i < 32; ++i) {
                float v = b2f(bufA[(wid*32 + i)*CMP + lane]);
                s1 += v; s2 += v*v;
            }
            atomicAdd(&stats[lane], s1);
            atomicAdd(&stats[64 + lane], s2);
        }
        __syncthreads();   // S2

        // ---- phase C: normalize + transpose -> pm xn (bufP1) ----
        {
            const float mu = stats[lane] * (1.f/192.f);
            const float is = rsqrtf(fmaxf(stats[64 + lane]*(1.f/192.f) - mu*mu, 0.f) + 1e-5f);
            #pragma unroll
            for (int oo = 0; oo < 4; ++oo) {
                s8v w;
                #pragma unroll
                for (int j = 0; j < 8; ++j) {
                    int c = wid*32 + oo*8 + j;
                    float v = (b2f(bufA[c*CMP + lane]) - mu) * is;
                    v = v * lng[c] + lnb[c];
                    w[j] = (short)f2b(v);
                }
                *(s8v*)(bufP1 + lane*PMP + swz(wid*4 + oo, lane)*8) = w;
            }
        }
        __syncthreads();   // S3

        // ---- GEMM1: y = pre_w * xn + pre_b -> bufP2 pm ----
        {
            f4v acc[2][4];
            #pragma unroll
            for (int j = 0; j < 2; ++j)
                #pragma unroll
                for (int nt = 0; nt < 4; ++nt) acc[j][nt] = (f4v){0.f,0.f,0.f,0.f};
            #pragma unroll
            for (int ks = 0; ks < 6; ++ks) {
                s8v b[4];
                #pragma unroll
                for (int nt = 0; nt < 4; ++nt) {
                    int p = nt*16 + l15;
                    b[nt] = *(const s8v*)(bufP1 + p*PMP + swz(ks*4 + quad, p)*8);
                }
                #pragma unroll
                for (int j = 0; j < 2; ++j) {
                    s8v a = *(const s8v*)(pre_wb + (size_t)((wid*2 + j)*16 + l15)*NCH + ks*32 + quad*8);
                    #pragma unroll
                    for (int nt = 0; nt < 4; ++nt)
                        acc[j][nt] = __builtin_amdgcn_mfma_f32_16x16x32_bf16(a, b[nt], acc[j][nt], 0, 0, 0);
                }
            }
            #pragma unroll
            for (int j = 0; j < 2; ++j) {
                int cc = (wid*2 + j)*16 + quad*4;
                f4v pb4 = *(const f4v*)(pre_b + cc);
                int oct = cc >> 3, half = (cc >> 2) & 1;
                #pragma unroll
                for (int nt = 0; nt < 4; ++nt) {
                    int p = nt*16 + l15;
                    s4v w;
                    #pragma unroll
                    for (int r = 0; r < 4; ++r)
                        w[r] = (short)f2b(acc[j][nt][r] + pb4[r]);
                    *(s4v*)(bufP2 + p*PMP + swz(oct, p)*8 + half*4) = w;
                }
            }
        }
        __syncthreads();   // S4

        // ---- GEMM2a: q & k merged (64 accs) ----
        {
            f4v aq[2][4], ak[2][4];
            #pragma unroll
            for (int j = 0; j < 2; ++j)
                #pragma unroll
                for (int nt = 0; nt < 4; ++nt) {
                    aq[j][nt] = (f4v){0.f,0.f,0.f,0.f};
                    ak[j][nt] = (f4v){0.f,0.f,0.f,0.f};
                }
            #pragma unroll
            for (int ks = 0; ks < 6; ++ks) {
                s8v b[4];
                #pragma unroll
                for (int nt = 0; nt < 4; ++nt) {
                    int p = nt*16 + l15;
                    b[nt] = *(const s8v*)(bufP2 + p*PMP + swz(ks*4 + quad, p)*8);
                }
                #pragma unroll
                for (int j = 0; j < 2; ++j) {
                    const unsigned short* wr = qkv_wb + (size_t)(wid*32 + j*16 + l15)*NCH + ks*32 + quad*8;
                    s8v a0 = *(const s8v*)(wr);
                    s8v a1 = *(const s8v*)(wr + (size_t)192*NCH);
                    #pragma unroll
                    for (int nt = 0; nt < 4; ++nt) {
                        aq[j][nt] = __builtin_amdgcn_mfma_f32_16x16x32_bf16(a0, b[nt], aq[j][nt], 0, 0, 0);
                        ak[j][nt] = __builtin_amdgcn_mfma_f32_16x16x32_bf16(a1, b[nt], ak[j][nt], 0, 0, 0);
                    }
                }
            }
            // store q -> bufA cm, k -> bufP1 cm (bufA free since S3, bufP1 free since S4)
            #pragma unroll
            for (int j = 0; j < 2; ++j)
                #pragma unroll
                for (int nt = 0; nt < 4; ++nt) {
                    int p = nt*16 + l15;
                    #pragma unroll
                    for (int r = 0; r < 4; ++r) {
                        int c = wid*32 + j*16 + quad*4 + r;
                        bufA[c*CMP + p]  = f2b(aq[j][nt][r]);
                        bufP1[c*CMP + p] = f2b(ak[j][nt][r]);
                    }
                }
        }
        __syncthreads();   // S5

        // ---- V pass (32 accs) + next-tile prefetch + sumsq + gram ----
        int tn = t_next_sh;
        if (tn < NTILES) {
            #pragma unroll
            for (int pass = 0; pass < 4; ++pass) {
                const float* gp = x + (size_t)(pass*48 + c0)*HW + tn*PT + oc8*8;
                xr[2*pass]   = *(const f4v*)(gp);
                xr[2*pass+1] = *(const f4v*)(gp + 4);
            }
        }
        f4v av[2][4];
        {
            #pragma unroll
            for (int j = 0; j < 2; ++j)
                #pragma unroll
                for (int nt = 0; nt < 4; ++nt) av[j][nt] = (f4v){0.f,0.f,0.f,0.f};
            #pragma unroll
            for (int ks = 0; ks < 6; ++ks) {
                s8v b[4];
                #pragma unroll
                for (int nt = 0; nt < 4; ++nt) {
                    int p = nt*16 + l15;
                    b[nt] = *(const s8v*)(bufP2 + p*PMP + swz(ks*4 + quad, p)*8);
                }
                #pragma unroll
                for (int j = 0; j < 2; ++j) {
                    s8v a2 = *(const s8v*)(qkv_wb + (size_t)(384 + wid*32 + j*16 + l15)*NCH + ks*32 + quad*8);
                    #pragma unroll
                    for (int nt = 0; nt < 4; ++nt)
                        av[j][nt] = __builtin_amdgcn_mfma_f32_16x16x32_bf16(a2, b[nt], av[j][nt], 0, 0, 0);
                }
            }
        }
        // sumsq of q,k rows
        {
            const unsigned short* src = (tid < 192) ? (bufA + tid*CMP) : (bufP1 + (tid - 192)*CMP);
            float s = 0.f;
            #pragma unroll
            for (int o = 0; o < 8; ++o) {
                s4v lo = *(const s4v*)(src + o*8);
                s4v hi = *(const s4v*)(src + o*8 + 4);
                #pragma unroll
                for (int e = 0; e < 4; ++e) {
                    float a = b2f((unsigned short)lo[e]);
                    float b = b2f((unsigned short)hi[e]);
                    s += a*a + b*b;
                }
            }
            sq_lds[tid] += s;
        }
        // gram accumulate (h = wid)
        #pragma unroll
        for (int g = 0; g < 4; ++g) {
            int dm = g >> 1, em = g & 1;
            const unsigned short* qrow = bufA  + (wid*32 + dm*16 + l15)*CMP;
            const unsigned short* krow = bufP1 + (wid*32 + em*16 + l15)*CMP;
            #pragma unroll
            for (int ks = 0; ks < 2; ++ks) {
                int off = ks*32 + quad*8;
                s4v alo = *(const s4v*)(qrow + off), ahi = *(const s4v*)(qrow + off + 4);
                s4v blo = *(const s4v*)(krow + off), bhi = *(const s4v*)(krow + off + 4);
                s8v a = __builtin_shufflevector(alo, ahi, 0,1,2,3,4,5,6,7);
                s8v b = __builtin_shufflevector(blo, bhi, 0,1,2,3,4,5,6,7);
                gacc[g] = __builtin_amdgcn_mfma_f32_16x16x32_bf16(a, b, gacc[g], 0, 0, 0);
            }
        }
        __syncthreads();   // S6: all y reads (V pass) done

        // av -> bufP2 pm (overwrites y)
        #pragma unroll
        for (int j = 0; j < 2; ++j) {
            int cc = wid*32 + j*16 + quad*4;
            int oct = cc >> 3, half = (cc >> 2) & 1;
            #pragma unroll
            for (int nt = 0; nt < 4; ++nt) {
                int p = nt*16 + l15;
                s4v w;
                #pragma unroll
                for (int r = 0; r < 4; ++r)
                    w[r] = (short)f2b(av[j][nt][r]);
                *(s4v*)(bufP2 + p*PMP + swz(oct, p)*8 + half*4) = w;
            }
        }
        __syncthreads();   // S7

        // ---- v global store (tile-contiguous packed format) ----
        #pragma unroll
        for (int q = 0; q < 4; ++q) {
            int idx = q*384 + tid;
            int p   = idx / 24;
            int col = (idx - p*24) * 8;
            s8v w = *(const s8v*)(bufP2 + p*PMP + col);
            *(s8v*)(v_out + (size_t)4*(idx >> 4)*HW + (size_t)128*t + (tid & 15)*8) = w;
        }
        t = tn;
    }

    #pragma unroll
    for (int g = 0; g < 4; ++g) {
        int dm = g >> 1, em = g & 1;
        #pragma unroll
        for (int r = 0; r < 4; ++r) {
            int d = dm*16 + quad*4 + r, e = em*16 + l15;
            atomicAdd(&gram_red[wid*1024 + d*32 + e], gacc[g][r]);
        }
    }
    atomicAdd(&sq_red[tid], sq_lds[tid]);
}

// ============================ K2 ============================
__global__ void gsa_k2(const float* __restrict__ gram_red, const float* __restrict__ sq_red,
                       const float* __restrict__ mn_w, const float* __restrict__ gating,
                       unsigned short* __restrict__ gm_out)
{
    __shared__ float attn[6144];
    __shared__ float mw[2048];
    __shared__ float inv[384];
    const int tid = threadIdx.x;
    for (int i = tid; i < 384; i += 256)
        inv[i] = 1.f / fmaxf(sqrtf(fmaxf(sq_red[i], 0.f)), 1e-12f);
    for (int i = tid; i < 2048; i += 256) mw[i] = mn_w[i];
    __syncthreads();
    for (int i = tid; i < 6144; i += 256) {
        int h = i >> 10, d = (i >> 5) & 31, e = i & 31;
        attn[i] = gram_red[i] * inv[h*32 + d] * inv[192 + h*32 + e];
    }
    __syncthreads();
    if (tid < 192) {
        int h = tid >> 5, d = tid & 31;
        float g1 = gating[h], g2 = gating[6 + h];
        const float* ar = attn + h*1024 + d*32;
        for (int e = 0; e < 32; ++e) {
            float m = 0.f, n = 0.f;
            for (int c2 = 0; c2 < 32; ++c2) {
                m += ar[c2] * mw[e*32 + c2];
                n += ar[c2] * mw[(e + 32)*32 + c2];
            }
            gm_out[h*1024 + d*32 + e] = f2b(g1*m + g2*n);
        }
    }
}

// ============================ K3 ============================
__global__ __launch_bounds__(384, 2) void gsa_k3(
    const float* __restrict__ cond,
    const float* __restrict__ x,
    const unsigned short* __restrict__ gm,
    const unsigned short* __restrict__ proj_wb,
    const unsigned short* v_in,     // u16 view of d_out
    float* out,                     // fp32 view of d_out
    unsigned int* __restrict__ ctr)
{
    __shared__ __align__(16) unsigned char smem[26112 + 25600 + 25600];
    __shared__ int t_next_sh;
    unsigned short* bufA = (unsigned short*)smem;                     // cm cond -> pm v -> cm bounce
    unsigned short* bufB = (unsigned short*)(smem + 26112);           // pm illu
    unsigned short* bufC = (unsigned short*)(smem + 26112 + 25600);   // pm sm

    const int tid  = threadIdx.x;
    const int wid  = tid >> 6;     // 0..5 == head
    const int lane = tid & 63;
    const int l15  = lane & 15;
    const int quad = lane >> 4;
    const int c0   = tid >> 3;
    const int oc8  = tid & 7;

    int t = blockIdx.x;
    f4v cr[8];
    s8v vr[4];
    #pragma unroll
    for (int pass = 0; pass < 4; ++pass) {
        const float* gp = cond + (size_t)(pass*48 + c0)*HW + t*PT + oc8*8;
        cr[2*pass]   = *(const f4v*)(gp);
        cr[2*pass+1] = *(const f4v*)(gp + 4);
    }
    #pragma unroll
    for (int q = 0; q < 4; ++q) {
        int idx = q*384 + tid;
        vr[q] = *(const s8v*)(v_in + (size_t)4*(idx >> 4)*HW + (size_t)128*t + (tid & 15)*8);
    }

    while (t < NTILES) {
        __syncthreads();   // S0: prev epilogue's bufA reads done
        if (tid == 0) t_next_sh = (int)atomicAdd(ctr + 1, 1u);
        // phase A: cr -> bufA cm
        #pragma unroll
        for (int pass = 0; pass < 4; ++pass) {
            int c = pass*48 + c0;
            s8v w;
            #pragma unroll
            for (int r = 0; r < 4; ++r) { w[r] = (short)f2b(cr[2*pass][r]); w[4+r] = (short)f2b(cr[2*pass+1][r]); }
            *(s8v*)(bufA + c*CMP + oc8*8) = w;
        }
        __syncthreads();   // S1
        // transpose -> bufB pm
        #pragma unroll
        for (int oo = 0; oo < 4; ++oo) {
            int oct = wid*4 + oo;
            s8v w;
            #pragma unroll
            for (int j = 0; j < 8; ++j)
                w[j] = (short)bufA[(oct*8 + j)*CMP + lane];
            *(s8v*)(bufB + lane*PMP + swz(oct, lane)*8) = w;
        }
        __syncthreads();   // S2
        // v stage: vr -> bufA pm (verbatim swizzled rows)
        #pragma unroll
        for (int q = 0; q < 4; ++q) {
            int idx = q*384 + tid;
            int p   = idx / 24;
            int col = (idx - p*24) * 8;
            *(s8v*)(bufA + p*PMP + col) = vr[q];
        }
        // prefetch next tile's cond + v
        int tn = t_next_sh;
        if (tn < NTILES) {
            #pragma unroll
            for (int pass = 0; pass < 4; ++pass) {
                const float* gp = cond + (size_t)(pass*48 + c0)*HW + tn*PT + oc8*8;
                cr[2*pass]   = *(const f4v*)(gp);
                cr[2*pass+1] = *(const f4v*)(gp + 4);
            }
            #pragma unroll
            for (int q = 0; q < 4; ++q) {
                int idx = q*384 + tid;
                vr[q] = *(const s8v*)(v_in + (size_t)4*(idx >> 4)*HW + (size_t)128*tn + (tid & 15)*8);
            }
        }
        __syncthreads();   // S3
        // mi MFMA + *v + softmax over head-dim -> bufC (h = wid)
        {
            const int h = wid;
            s8v a0 = *(const s8v*)(gm + h*1024 + l15*32 + quad*8);
            s8v a1 = *(const s8v*)(gm + h*1024 + (16 + l15)*32 + quad*8);
            #pragma unroll
            for (int nt = 0; nt < 4; ++nt) {
                int p = nt*16 + l15;
                s8v b = *(const s8v*)(bufB + p*PMP + swz(h*4 + quad, p)*8);
                f4v z = (f4v){0.f,0.f,0.f,0.f};
                f4v m0 = __builtin_amdgcn_mfma_f32_16x16x32_bf16(a0, b, z, 0, 0, 0);
                f4v m1 = __builtin_amdgcn_mfma_f32_16x16x32_bf16(a1, b, z, 0, 0, 0);
                int oct0 = h*4 + (quad >> 1), hf = (quad & 1)*4;
                s4v v0 = *(const s4v*)(bufA + p*PMP + swz(oct0, p)*8 + hf);
                s4v v1 = *(const s4v*)(bufA + p*PMP + swz(oct0 + 2, p)*8 + hf);
                float tv[8];
                #pragma unroll
                for (int r = 0; r < 4; ++r) {
                    tv[r]     = m0[r] * b2f((unsigned short)v0[r]);
                    tv[4 + r] = m1[r] * b2f((unsigned short)v1[r]);
                }
                float mx = tv[0];
                #pragma unroll
                for (int r = 1; r < 8; ++r) mx = fmaxf(mx, tv[r]);
                mx = fmaxf(mx, __shfl_xor(mx, 16));
                mx = fmaxf(mx, __shfl_xor(mx, 32));
                float s = 0.f;
                #pragma unroll
                for (int r = 0; r < 8; ++r) { tv[r] = __expf(tv[r] - mx); s += tv[r]; }
                s += __shfl_xor(s, 16);
                s += __shfl_xor(s, 32);
                float is = 1.f / s;
                s4v w0, w1;
                #pragma unroll
                for (int r = 0; r < 4; ++r) {
                    w0[r] = (short)f2b(tv[r] * is);
                    w1[r] = (short)f2b(tv[4 + r] * is);
                }
                int ca = h*32 + quad*4, cb = ca + 16;
                *(s4v*)(bufC + p*PMP + swz(ca >> 3, p)*8 + ((ca >> 2) & 1)*4) = w0;
                *(s4v*)(bufC + p*PMP + swz(cb >> 3, p)*8 + ((cb >> 2) & 1)*4) = w1;
            }
        }
        __syncthreads();   // S4
        // GEMM4 (proj) + x residual prefetch + bounce
        {
            f4v xr[8];
            #pragma unroll
            for (int pass = 0; pass < 4; ++pass) {
                const float* gp = x + (size_t)(pass*48 + c0)*HW + t*PT + oc8*8;
                xr[2*pass]   = *(const f4v*)(gp);
                xr[2*pass+1] = *(const f4v*)(gp + 4);
            }
            f4v acc[2][4];
            #pragma unroll
            for (int j = 0; j < 2; ++j)
                #pragma unroll
                for (int nt = 0; nt < 4; ++nt) acc[j][nt] = (f4v){0.f,0.f,0.f,0.f};
            #pragma unroll
            for (int ks = 0; ks < 6; ++ks) {
                s8v b[4];
                #pragma unroll
                for (int nt = 0; nt < 4; ++nt) {
                    int p = nt*16 + l15;
                    b[nt] = *(const s8v*)(bufC + p*PMP + swz(ks*4 + quad, p)*8);
                }
                #pragma unroll
                for (int j = 0; j < 2; ++j) {
                    s8v a = *(const s8v*)(proj_wb + (size_t)((wid*2 + j)*16 + l15)*NCH + ks*32 + quad*8);
                    #pragma unroll
                    for (int nt = 0; nt < 4; ++nt)
                        acc[j][nt] = __builtin_amdgcn_mfma_f32_16x16x32_bf16(a, b[nt], acc[j][nt], 0, 0, 0);
                }
            }
            // bounce: accs -> bufA cm (v reads finished pre-S4)
            #pragma unroll
            for (int j = 0; j < 2; ++j)
                #pragma unroll
                for (int nt = 0; nt < 4; ++nt) {
                    int p = nt*16 + l15;
                    #pragma unroll
                    for (int r = 0; r < 4; ++r) {
                        int c = wid*32 + j*16 + quad*4 + r;
                        bufA[c*CMP + p] = f2b(acc[j][nt][r]);
                    }
                }
            __syncthreads();   // S5
            // epilogue: out = proj + x
            #pragma unroll
            for (int pass = 0; pass < 4; ++pass) {
                int c = pass*48 + c0;
                f4v o0, o1;
                #pragma unroll
                for (int r = 0; r < 4; ++r) {
                    o0[r] = b2f(bufA[c*CMP + oc8*8 + r])     + xr[2*pass][r];
                    o1[r] = b2f(bufA[c*CMP + oc8*8 + 4 + r]) + xr[2*pass+1][r];
                }
                float* op = out + (size_t)c*HW + t*PT + oc8*8;
                *(f4v*)(op)     = o0;
                *(f4v*)(op + 4) = o1;
            }
        }
        t = tn;
    }
}

// ============================ launch ============================
extern "C" void kernel_launch(void* const* d_in, const int* in_sizes, int n_in,
                              void* d_out, int out_size, void* d_ws, size_t ws_size,
                              hipStream_t stream)
{
    (void)in_sizes; (void)n_in; (void)out_size; (void)ws_size;
    const float* x      = (const float*)d_in[0];
    const float* cond   = (const float*)d_in[1];
    const float* lng    = (const float*)d_in[2];
    const float* lnb    = (const float*)d_in[3];
    const float* pre_w  = (const float*)d_in[4];
    const float* pre_b  = (const float*)d_in[5];
    const float* qkv_w  = (const float*)d_in[6];
    const float* mn_w   = (const float*)d_in[7];
    const float* gating = (const float*)d_in[8];
    const float* proj_w = (const float*)d_in[9];

    // workspace layout:
    //   [0,24576)        gram_red (6144 f32)
    //   [24576,26112)    sq_red   (384 f32)
    //   [26112,38400)    gm       (6144 bf16)
    //   [38400,407040)   wbf: pre_w_bf16 | qkv_w_bf16 | proj_w_bf16
    //   [407040,407048)  tickets: ctr[0]=K1, ctr[1]=K3
    char* ws = (char*)d_ws;
    float* gram_red = (float*)ws;
    float* sq_red   = (float*)(ws + 24576);
    unsigned short* gm  = (unsigned short*)(ws + 26112);
    unsigned short* wbf = (unsigned short*)(ws + 38400);
    unsigned int* ctr   = (unsigned int*)(ws + 407040);
    unsigned short* pre_wb  = wbf;
    unsigned short* qkv_wb  = wbf + 36864;
    unsigned short* proj_wb = wbf + 147456;

    gsa_prep<<<432,  256, 0, stream>>>(pre_w, qkv_w, proj_w, wbf, gram_red, ctr);
    gsa_k1 <<<GRID,  384, 0, stream>>>(x, lng, lnb, pre_wb, pre_b, qkv_wb,
                                       (unsigned short*)d_out, gram_red, sq_red, ctr);
    gsa_k2 <<<1,     256, 0, stream>>>(gram_red, sq_red, mn_w, gating, gm);
    gsa_k3 <<<GRID,  384, 0, stream>>>(cond, x, gm, proj_wb,
                                       (const unsigned short*)d_out, (float*)d_out, ctr);
}